// Round 2
// baseline (2240.333 us; speedup 1.0000x reference)
//
#include <hip/hip_runtime.h>

#define LSEQ   4096
#define EMBED  1024
#define NHEADS 16
#define HDIM   64
#define QKV_N  3072

// ---------------------------------------------------------------------------
// Generalized tiled fp32 GEMM + bias: C = A @ B + bias
// A: MxK (lda), B: KxN (ldb), C: MxN (ldc), bias: N
// 128x128 tile, BK=16, 256 threads, 8x8 micro-tile.
// ---------------------------------------------------------------------------
template<int BM, int BN, int BK>
__global__ __launch_bounds__(256)
void gemm_bias_kernel(const float* __restrict__ A, const float* __restrict__ B,
                      const float* __restrict__ bias, float* __restrict__ C,
                      int M, int N, int K, int lda, int ldb, int ldc)
{
    __shared__ float As[BK][BM + 4];
    __shared__ float Bs[BK][BN + 4];

    const int t = threadIdx.x;
    const int rowBase = blockIdx.y * BM;
    const int colBase = blockIdx.x * BN;
    const int tr = t >> 4, tc = t & 15;          // 16x16 thread grid
    const int ar = t >> 2, ac4 = (t & 3) << 2;   // A tile load map
    const int bk = t >> 5, bc4 = (t & 31) << 2;  // B tile load map

    float acc[8][8] = {};

    for (int k0 = 0; k0 < K; k0 += BK) {
        float4 a0 = *reinterpret_cast<const float4*>(&A[(size_t)(rowBase + ar) * lda + k0 + ac4]);
        float4 a1 = *reinterpret_cast<const float4*>(&A[(size_t)(rowBase + ar + 64) * lda + k0 + ac4]);
        float4 b0 = *reinterpret_cast<const float4*>(&B[(size_t)(k0 + bk) * ldb + colBase + bc4]);
        float4 b1 = *reinterpret_cast<const float4*>(&B[(size_t)(k0 + bk + 8) * ldb + colBase + bc4]);

        __syncthreads();   // previous iteration's reads must finish before overwrite
        As[ac4 + 0][ar] = a0.x; As[ac4 + 1][ar] = a0.y;
        As[ac4 + 2][ar] = a0.z; As[ac4 + 3][ar] = a0.w;
        As[ac4 + 0][ar + 64] = a1.x; As[ac4 + 1][ar + 64] = a1.y;
        As[ac4 + 2][ar + 64] = a1.z; As[ac4 + 3][ar + 64] = a1.w;
        *reinterpret_cast<float4*>(&Bs[bk][bc4])     = b0;
        *reinterpret_cast<float4*>(&Bs[bk + 8][bc4]) = b1;
        __syncthreads();

        #pragma unroll
        for (int k = 0; k < BK; ++k) {
            float4 A0 = *reinterpret_cast<const float4*>(&As[k][tr * 8]);
            float4 A1 = *reinterpret_cast<const float4*>(&As[k][tr * 8 + 4]);
            float4 B0 = *reinterpret_cast<const float4*>(&Bs[k][tc * 8]);
            float4 B1 = *reinterpret_cast<const float4*>(&Bs[k][tc * 8 + 4]);
            float av[8] = {A0.x, A0.y, A0.z, A0.w, A1.x, A1.y, A1.z, A1.w};
            float bv[8] = {B0.x, B0.y, B0.z, B0.w, B1.x, B1.y, B1.z, B1.w};
            #pragma unroll
            for (int i = 0; i < 8; ++i)
                #pragma unroll
                for (int j = 0; j < 8; ++j)
                    acc[i][j] = fmaf(av[i], bv[j], acc[i][j]);
        }
    }

    const int row0 = rowBase + tr * 8;
    const int col0 = colBase + tc * 8;
    #pragma unroll
    for (int i = 0; i < 8; ++i) {
        #pragma unroll
        for (int j4 = 0; j4 < 2; ++j4) {
            float4 o;
            o.x = acc[i][j4 * 4 + 0] + bias[col0 + j4 * 4 + 0];
            o.y = acc[i][j4 * 4 + 1] + bias[col0 + j4 * 4 + 1];
            o.z = acc[i][j4 * 4 + 2] + bias[col0 + j4 * 4 + 2];
            o.w = acc[i][j4 * 4 + 3] + bias[col0 + j4 * 4 + 3];
            *reinterpret_cast<float4*>(&C[(size_t)(row0 + i) * ldc + col0 + j4 * 4]) = o;
        }
    }
}

// ---------------------------------------------------------------------------
// kv partial per (h, chunk) for ONE batch. chunk = 256 L-rows, 4 sub-tiles of 64.
// kvb: 4096 x 2048 (k at col h*64, v at col 1024 + h*64)
// Fuses: RoPE(k) -> k' = relu(k_rot @ proj[h]) * mask -> kv += k'^T (v*mask).
// partial layout: [h][chunk][4160]  (4096 = kv 64x64 row-major [m][d], +64 = ksum)
// ---------------------------------------------------------------------------
__global__ __launch_bounds__(256)
void kv_partial_kernel(const float* __restrict__ kvb, const float* __restrict__ cosb,
                       const float* __restrict__ sinb, const float* __restrict__ maskb,
                       const float* __restrict__ proj, float* __restrict__ partial)
{
    const int chunk = blockIdx.x;   // 0..15
    const int h     = blockIdx.y;   // 0..15
    const int t = threadIdx.x;

    __shared__ float bufA[64][68];  // k_rot, then v (reused)
    __shared__ float kp[64][68];    // k'
    __shared__ float pj[64][64];    // proj[h], [d][m]

    for (int i = t; i < 1024; i += 256)
        *reinterpret_cast<float4*>(&pj[0][0] + (size_t)i * 4) =
            *reinterpret_cast<const float4*>(proj + (size_t)h * 4096 + (size_t)i * 4);

    const int m  = t >> 2;          // 0..63
    const int d0 = (t & 3) << 4;    // 0,16,32,48
    float acc[16] = {};
    float ks = 0.f;

    for (int sub = 0; sub < 4; ++sub) {
        const int rowL = chunk * 256 + sub * 64;  // sequence position of tile start
        __syncthreads();  // guard bufA/kp reuse against previous sub's reads

        // RoPE-load K tile: 64 rows x 32 pairs
        #pragma unroll
        for (int i = 0; i < 8; ++i) {
            int p = t + i * 256;
            int l = p >> 5, i2 = p & 31;
            size_t base = (size_t)(rowL + l) * 2048 + h * HDIM + 2 * i2;
            float kr = kvb[base], ki = kvb[base + 1];
            float c = cosb[(size_t)(rowL + l) * 32 + i2];
            float s = sinb[(size_t)(rowL + l) * 32 + i2];
            bufA[l][2 * i2]     = kr * c - ki * s;
            bufA[l][2 * i2 + 1] = kr * s + ki * c;
        }
        __syncthreads();

        // k' = relu(k_rot @ proj) * mask
        {
            int l = t >> 2, m0 = (t & 3) << 4;
            float a[16] = {};
            for (int d = 0; d < 64; ++d) {
                float kl = bufA[l][d];
                const float* pr = &pj[d][m0];
                #pragma unroll
                for (int j = 0; j < 16; ++j) a[j] = fmaf(kl, pr[j], a[j]);
            }
            float mv = maskb[rowL + l];
            #pragma unroll
            for (int j = 0; j < 16; ++j) kp[l][m0 + j] = fmaxf(a[j], 0.f) * mv;
        }
        __syncthreads();

        // load masked V into bufA
        #pragma unroll
        for (int i = 0; i < 4; ++i) {
            int idx = t + i * 256;              // float4 index among 1024
            int l = idx >> 4, dd = (idx & 15) << 2;
            float4 v = *reinterpret_cast<const float4*>(
                &kvb[(size_t)(rowL + l) * 2048 + 1024 + h * HDIM + dd]);
            float mv = maskb[rowL + l];
            v.x *= mv; v.y *= mv; v.z *= mv; v.w *= mv;
            *reinterpret_cast<float4*>(&bufA[l][dd]) = v;
        }
        __syncthreads();

        // accumulate partial kv[m][d0..d0+15] and ksum[m]
        for (int l = 0; l < 64; ++l) {
            float kl = kp[l][m];
            ks += kl;
            const float* vr = &bufA[l][d0];
            #pragma unroll
            for (int j = 0; j < 16; ++j) acc[j] = fmaf(kl, vr[j], acc[j]);
        }
    }

    float* dst = partial + ((size_t)h * 16 + chunk) * 4160;
    #pragma unroll
    for (int j4 = 0; j4 < 4; ++j4) {
        float4 o = {acc[j4 * 4 + 0], acc[j4 * 4 + 1], acc[j4 * 4 + 2], acc[j4 * 4 + 3]};
        *reinterpret_cast<float4*>(&dst[m * 64 + d0 + j4 * 4]) = o;
    }
    if ((t & 3) == 0) dst[4096 + m] = ks;
}

// Reduce 16 chunk partials -> kv (64x64) + ksum (64) per head
__global__ __launch_bounds__(256)
void kv_reduce_kernel(const float* __restrict__ partial, float* __restrict__ kvout)
{
    const int h = blockIdx.x;
    const int t = threadIdx.x;
    for (int idx = t; idx < 4160; idx += 256) {
        float s = 0.f;
        for (int c = 0; c < 16; ++c)
            s += partial[((size_t)h * 16 + c) * 4160 + idx];
        kvout[(size_t)h * 4160 + idx] = s;
    }
}

// ---------------------------------------------------------------------------
// context per (h, 64-row L tile) for ONE batch:
// RoPE(q) -> q' = relu(q_rot @ proj[h]) -> ctx = (q' @ kv) / (q'.ksum + 1e-4)
// qb: 4096 x 1024 (q at col h*64); ctxb: 4096 x 1024 written at col h*64.
// ---------------------------------------------------------------------------
__global__ __launch_bounds__(256)
void context_kernel(const float* __restrict__ qb, const float* __restrict__ cosb,
                    const float* __restrict__ sinb, const float* __restrict__ proj,
                    const float* __restrict__ kvsum, float* __restrict__ ctxb)
{
    const int lt = blockIdx.x;   // 0..63
    const int h  = blockIdx.y;   // 0..15
    const int t = threadIdx.x;

    __shared__ float bufA[64][68];  // q_rot, then reused for kv
    __shared__ float qp[64][68];    // q'
    __shared__ float pj[64][64];
    __shared__ float ksum[64];

    for (int i = t; i < 1024; i += 256)
        *reinterpret_cast<float4*>(&pj[0][0] + (size_t)i * 4) =
            *reinterpret_cast<const float4*>(proj + (size_t)h * 4096 + (size_t)i * 4);
    if (t < 64) ksum[t] = kvsum[(size_t)h * 4160 + 4096 + t];

    const int rowL = lt * 64;
    // RoPE-load Q tile
    #pragma unroll
    for (int i = 0; i < 8; ++i) {
        int p = t + i * 256;
        int l = p >> 5, i2 = p & 31;
        size_t base = (size_t)(rowL + l) * 1024 + h * HDIM + 2 * i2;
        float qr = qb[base], qi = qb[base + 1];
        float c = cosb[(size_t)(rowL + l) * 32 + i2];
        float s = sinb[(size_t)(rowL + l) * 32 + i2];
        bufA[l][2 * i2]     = qr * c - qi * s;
        bufA[l][2 * i2 + 1] = qr * s + qi * c;
    }
    __syncthreads();

    // q' = relu(q_rot @ proj)
    {
        int l = t >> 2, m0 = (t & 3) << 4;
        float a[16] = {};
        for (int d = 0; d < 64; ++d) {
            float ql = bufA[l][d];
            const float* pr = &pj[d][m0];
            #pragma unroll
            for (int j = 0; j < 16; ++j) a[j] = fmaf(ql, pr[j], a[j]);
        }
        #pragma unroll
        for (int j = 0; j < 16; ++j) qp[l][m0 + j] = fmaxf(a[j], 0.f);
    }
    __syncthreads();

    // overwrite bufA with kv[m][d]
    #pragma unroll
    for (int i = 0; i < 4; ++i) {
        int idx = t + i * 256;
        int mm = idx >> 4, dd = (idx & 15) << 2;
        *reinterpret_cast<float4*>(&bufA[mm][dd]) =
            *reinterpret_cast<const float4*>(&kvsum[(size_t)h * 4160 + mm * 64 + dd]);
    }
    __syncthreads();

    // ctx = (q' @ kv) / (q'.ksum + 1e-4)
    {
        int l = t >> 2, d0 = (t & 3) << 4;
        float a[16] = {};
        float nrm = 0.f;
        for (int mm = 0; mm < 64; ++mm) {
            float qv = qp[l][mm];
            nrm = fmaf(qv, ksum[mm], nrm);
            const float* kr = &bufA[mm][d0];
            #pragma unroll
            for (int j = 0; j < 16; ++j) a[j] = fmaf(qv, kr[j], a[j]);
        }
        float inv = 1.0f / (nrm + 1e-4f);
        size_t orow = (size_t)(rowL + l) * 1024 + h * HDIM + d0;
        #pragma unroll
        for (int j4 = 0; j4 < 4; ++j4) {
            float4 o = {a[j4 * 4 + 0] * inv, a[j4 * 4 + 1] * inv,
                        a[j4 * 4 + 2] * inv, a[j4 * 4 + 3] * inv};
            *reinterpret_cast<float4*>(&ctxb[orow + j4 * 4]) = o;
        }
    }
}

extern "C" void kernel_launch(void* const* d_in, const int* in_sizes, int n_in,
                              void* d_out, int out_size, void* d_ws, size_t ws_size,
                              hipStream_t stream)
{
    const float* x    = (const float*)d_in[0];
    const float* fcos = (const float*)d_in[1];
    const float* fsin = (const float*)d_in[2];
    const float* mask = (const float*)d_in[3];
    const float* Wqkv = (const float*)d_in[4];
    const float* bqkv = (const float*)d_in[5];
    const float* proj = (const float*)d_in[6];
    const float* Wout = (const float*)d_in[7];
    const float* bout = (const float*)d_in[8];
    float* out = (float*)d_out;

    // Scratch layout (floats), total 13,714,432 fl = 54.9 MB:
    float* ws    = (float*)d_ws;
    float* bufKV = ws;                          // 4096*2048 = 8,388,608 (K,V; later reused for Q)
    float* ctx_b = bufKV + (size_t)4096 * 2048; // 4096*1024 = 4,194,304
    float* part  = ctx_b + (size_t)4096 * 1024; // 16*16*4160 = 1,064,960
    float* kvsum = part + (size_t)16 * 16 * 4160; // 16*4160 = 66,560

    for (int b = 0; b < 4; ++b) {
        const float* xb = x + (size_t)b * 4096 * 1024;

        // K,V = x_b @ Wqkv[:,1024:3072] + bqkv[1024:]
        gemm_bias_kernel<128, 128, 16><<<dim3(2048 / 128, 4096 / 128), 256, 0, stream>>>(
            xb, Wqkv + 1024, bqkv + 1024, bufKV, 4096, 2048, 1024, 1024, QKV_N, 2048);

        // partial kv/ksum (fused RoPE + proj + relu + mask on K, masked V)
        kv_partial_kernel<<<dim3(16, 16), 256, 0, stream>>>(
            bufKV, fcos, fsin, mask + (size_t)b * 4096, proj, part);

        // reduce partials
        kv_reduce_kernel<<<dim3(16), 256, 0, stream>>>(part, kvsum);

        // Q = x_b @ Wqkv[:,0:1024] + bqkv[0:1024]  (overwrites bufKV; K/V reads done)
        gemm_bias_kernel<128, 128, 16><<<dim3(1024 / 128, 4096 / 128), 256, 0, stream>>>(
            xb, Wqkv, bqkv, bufKV, 4096, 1024, 1024, 1024, QKV_N, 1024);

        // context + normalization (fused RoPE + proj + relu on Q)
        context_kernel<<<dim3(64, 16), 256, 0, stream>>>(
            bufKV, fcos, fsin, proj, kvsum, ctx_b);

        // out_b = ctx_b @ Wout + bout
        gemm_bias_kernel<128, 128, 16><<<dim3(1024 / 128, 4096 / 128), 256, 0, stream>>>(
            ctx_b, Wout, bout, out + (size_t)b * 4096 * 1024, 4096, 1024, 1024, 1024, 1024, 1024);
    }
}

// Round 3
// 1184.541 us; speedup vs baseline: 1.8913x; 1.8913x over previous
//
#include <hip/hip_runtime.h>

#define LSEQ   4096
#define EMBED  1024
#define NHEADS 16
#define HDIM   64
#define QKV_N  3072

typedef __attribute__((ext_vector_type(8))) short bf16x8;
typedef __attribute__((ext_vector_type(4))) float f32x4;

// round-to-nearest-even fp32 -> bf16 (bit pattern), no header dependence
__device__ inline unsigned short bf16_rne(float x) {
    unsigned int u = __float_as_uint(x);
    unsigned int r = (u + 0x7fffu + ((u >> 16) & 1u)) >> 16;
    return (unsigned short)r;
}
__device__ inline float bf16_to_f32(unsigned short h) {
    return __uint_as_float(((unsigned int)h) << 16);
}

// ---------------------------------------------------------------------------
// Convert contiguous fp32 -> hi/lo bf16 arrays. n multiple of 1024.
// ---------------------------------------------------------------------------
__global__ __launch_bounds__(256)
void convert_hilo(const float* __restrict__ in, unsigned short* __restrict__ hi,
                  unsigned short* __restrict__ lo, int n)
{
    int i = (blockIdx.x * 256 + threadIdx.x) << 2;
    if (i >= n) return;
    float4 v = *reinterpret_cast<const float4*>(&in[i]);
    float a[4] = {v.x, v.y, v.z, v.w};
    unsigned short hh[4], ll[4];
    #pragma unroll
    for (int j = 0; j < 4; ++j) {
        hh[j] = bf16_rne(a[j]);
        ll[j] = bf16_rne(a[j] - bf16_to_f32(hh[j]));
    }
    *reinterpret_cast<ushort4*>(&hi[i]) = make_ushort4(hh[0], hh[1], hh[2], hh[3]);
    *reinterpret_cast<ushort4*>(&lo[i]) = make_ushort4(ll[0], ll[1], ll[2], ll[3]);
}

// ---------------------------------------------------------------------------
// Convert fp32 W[K][N] -> TRANSPOSED hi/lo bf16 Wt[N][K] (for B-operand).
// 64x64 LDS tile transpose. K,N multiples of 64.
// ---------------------------------------------------------------------------
__global__ __launch_bounds__(256)
void convert_T_hilo(const float* __restrict__ in, unsigned short* __restrict__ hi,
                    unsigned short* __restrict__ lo, int K, int N)
{
    __shared__ float tile[64][65];
    const int n0 = blockIdx.x * 64, k0 = blockIdx.y * 64;
    const int t = threadIdx.x;
    #pragma unroll
    for (int i = 0; i < 16; ++i) {
        int idx = t + i * 256;           // 0..4095
        int r = idx >> 6, c = idx & 63;  // k-local, n-local
        tile[r][c] = in[(size_t)(k0 + r) * N + n0 + c];
    }
    __syncthreads();
    #pragma unroll
    for (int i = 0; i < 16; ++i) {
        int idx = t + i * 256;
        int r = idx >> 6, c = idx & 63;  // n-local, k-local
        float v = tile[c][r];
        unsigned short h = bf16_rne(v);
        unsigned short l = bf16_rne(v - bf16_to_f32(h));
        size_t o = (size_t)(n0 + r) * K + k0 + c;
        hi[o] = h;
        lo[o] = l;
    }
}

// ---------------------------------------------------------------------------
// bf16x3 split GEMM: C = A @ B^T_stored + bias   (logical C = A @ B + bias)
// A_hi/A_lo: [M][K] bf16 row-major (lda=K). Bt_hi/Bt_lo: [N][K] bf16 (ldb=K).
// C fp32 [M][ldc]. 128x128 tile, BK=32, 4 waves, mfma_f32_16x16x32_bf16,
// 3 products: ah*bh + ah*bl + al*bh. global_load_lds(16B) staging, linear LDS.
// M,N multiples of 128; K multiple of 32.
// ---------------------------------------------------------------------------
__global__ __launch_bounds__(256)
void gemm3_kernel(const unsigned short* __restrict__ Ah, const unsigned short* __restrict__ Al,
                  const unsigned short* __restrict__ Bh, const unsigned short* __restrict__ Bl,
                  const float* __restrict__ bias, float* __restrict__ C,
                  int K, int ldc)
{
    __shared__ __align__(16) unsigned short lds[4][128 * 32];  // Ah,Al,Bh,Bl tiles (32 KB)

    const int t = threadIdx.x;
    const int wave = t >> 6, lane = t & 63;
    const int wr = wave >> 1, wc = wave & 1;
    const int rowBase = blockIdx.y * 128;
    const int colBase = blockIdx.x * 128;

    // staging: wave w copies one whole [128][32] tile (8 issues x 64 lanes x 16B)
    const unsigned short* src = (wave == 0) ? Ah : (wave == 1) ? Al : (wave == 2) ? Bh : Bl;
    const int tileRow0 = (wave < 2) ? rowBase : colBase;
    const int srow = lane >> 2;          // 0..15 within a 16-row group
    const int scol = (lane & 3) << 3;    // k-offset in elements: 0,8,16,24

    const int fr = lane & 15, fq = lane >> 4;

    f32x4 acc[4][4] = {};

    for (int k0 = 0; k0 < K; k0 += 32) {
        #pragma unroll
        for (int i = 0; i < 8; ++i) {
            const unsigned short* g =
                src + (size_t)(tileRow0 + i * 16 + srow) * K + k0 + scol;
            __builtin_amdgcn_global_load_lds(
                (const __attribute__((address_space(1))) void*)g,
                (__attribute__((address_space(3))) void*)&lds[wave][i * 512],
                16, 0, 0);
        }
        __syncthreads();   // drains vmcnt before barrier -> tiles visible

        bf16x8 ah[4], al[4], bh[4], bl[4];
        #pragma unroll
        for (int m = 0; m < 4; ++m) {
            int off = (wr * 64 + m * 16 + fr) * 32 + fq * 8;
            ah[m] = *reinterpret_cast<const bf16x8*>(&lds[0][off]);
            al[m] = *reinterpret_cast<const bf16x8*>(&lds[1][off]);
        }
        #pragma unroll
        for (int n = 0; n < 4; ++n) {
            int off = (wc * 64 + n * 16 + fr) * 32 + fq * 8;
            bh[n] = *reinterpret_cast<const bf16x8*>(&lds[2][off]);
            bl[n] = *reinterpret_cast<const bf16x8*>(&lds[3][off]);
        }
        #pragma unroll
        for (int m = 0; m < 4; ++m)
            #pragma unroll
            for (int n = 0; n < 4; ++n) {
                acc[m][n] = __builtin_amdgcn_mfma_f32_16x16x32_bf16(ah[m], bh[n], acc[m][n], 0, 0, 0);
                acc[m][n] = __builtin_amdgcn_mfma_f32_16x16x32_bf16(ah[m], bl[n], acc[m][n], 0, 0, 0);
                acc[m][n] = __builtin_amdgcn_mfma_f32_16x16x32_bf16(al[m], bh[n], acc[m][n], 0, 0, 0);
            }
        __syncthreads();   // all reads done before next stage overwrites
    }

    // epilogue: C/D frag mapping col=lane&15, row=(lane>>4)*4+reg (m89-verified)
    #pragma unroll
    for (int m = 0; m < 4; ++m) {
        #pragma unroll
        for (int n = 0; n < 4; ++n) {
            int col = colBase + wc * 64 + n * 16 + fr;
            float bv = bias[col];
            #pragma unroll
            for (int r = 0; r < 4; ++r) {
                int row = rowBase + wr * 64 + m * 16 + fq * 4 + r;
                C[(size_t)row * ldc + col] = acc[m][n][r] + bv;
            }
        }
    }
}

// ---------------------------------------------------------------------------
// kv partial per (h, chunk) for ONE L-half (2048 rows). chunk = 256 rows.
// kvb: [2048][2048] fp32 (k at col h*64, v at col 1024 + h*64).
// cos/sin/mask pointers pre-offset to the half. first=1 -> overwrite partials.
// partial layout: [h][8 chunks][4160] (4096 = kv [m][d], +64 = ksum)
// ---------------------------------------------------------------------------
__global__ __launch_bounds__(256)
void kv_partial_kernel(const float* __restrict__ kvb, const float* __restrict__ cosb,
                       const float* __restrict__ sinb, const float* __restrict__ maskb,
                       const float* __restrict__ proj, float* __restrict__ partial,
                       int first)
{
    const int chunk = blockIdx.x;   // 0..7
    const int h     = blockIdx.y;   // 0..15
    const int t = threadIdx.x;

    __shared__ float bufA[64][68];  // k_rot, then v (reused)
    __shared__ float kp[64][68];    // k'
    __shared__ float pj[64][64];    // proj[h], [d][m]

    for (int i = t; i < 1024; i += 256)
        *reinterpret_cast<float4*>(&pj[0][0] + (size_t)i * 4) =
            *reinterpret_cast<const float4*>(proj + (size_t)h * 4096 + (size_t)i * 4);

    const int m  = t >> 2;          // 0..63
    const int d0 = (t & 3) << 4;    // 0,16,32,48
    float acc[16] = {};
    float ks = 0.f;

    for (int sub = 0; sub < 4; ++sub) {
        const int rowL = chunk * 256 + sub * 64;
        __syncthreads();

        // RoPE-load K tile: 64 rows x 32 pairs
        #pragma unroll
        for (int i = 0; i < 8; ++i) {
            int p = t + i * 256;
            int l = p >> 5, i2 = p & 31;
            size_t base = (size_t)(rowL + l) * 2048 + h * HDIM + 2 * i2;
            float kr = kvb[base], ki = kvb[base + 1];
            float c = cosb[(size_t)(rowL + l) * 32 + i2];
            float s = sinb[(size_t)(rowL + l) * 32 + i2];
            bufA[l][2 * i2]     = kr * c - ki * s;
            bufA[l][2 * i2 + 1] = kr * s + ki * c;
        }
        __syncthreads();

        // k' = relu(k_rot @ proj) * mask
        {
            int l = t >> 2, m0 = (t & 3) << 4;
            float a[16] = {};
            for (int d = 0; d < 64; ++d) {
                float kl = bufA[l][d];
                const float* pr = &pj[d][m0];
                #pragma unroll
                for (int j = 0; j < 16; ++j) a[j] = fmaf(kl, pr[j], a[j]);
            }
            float mv = maskb[rowL + l];
            #pragma unroll
            for (int j = 0; j < 16; ++j) kp[l][m0 + j] = fmaxf(a[j], 0.f) * mv;
        }
        __syncthreads();

        // load masked V into bufA
        #pragma unroll
        for (int i = 0; i < 4; ++i) {
            int idx = t + i * 256;
            int l = idx >> 4, dd = (idx & 15) << 2;
            float4 v = *reinterpret_cast<const float4*>(
                &kvb[(size_t)(rowL + l) * 2048 + 1024 + h * HDIM + dd]);
            float mv = maskb[rowL + l];
            v.x *= mv; v.y *= mv; v.z *= mv; v.w *= mv;
            *reinterpret_cast<float4*>(&bufA[l][dd]) = v;
        }
        __syncthreads();

        for (int l = 0; l < 64; ++l) {
            float kl = kp[l][m];
            ks += kl;
            const float* vr = &bufA[l][d0];
            #pragma unroll
            for (int j = 0; j < 16; ++j) acc[j] = fmaf(kl, vr[j], acc[j]);
        }
    }

    float* dst = partial + ((size_t)h * 8 + chunk) * 4160;
    if (first) {
        #pragma unroll
        for (int j4 = 0; j4 < 4; ++j4) {
            float4 o = {acc[j4 * 4 + 0], acc[j4 * 4 + 1], acc[j4 * 4 + 2], acc[j4 * 4 + 3]};
            *reinterpret_cast<float4*>(&dst[m * 64 + d0 + j4 * 4]) = o;
        }
        if ((t & 3) == 0) dst[4096 + m] = ks;
    } else {
        #pragma unroll
        for (int j4 = 0; j4 < 4; ++j4) {
            float4 p = *reinterpret_cast<const float4*>(&dst[m * 64 + d0 + j4 * 4]);
            float4 o = {p.x + acc[j4 * 4 + 0], p.y + acc[j4 * 4 + 1],
                        p.z + acc[j4 * 4 + 2], p.w + acc[j4 * 4 + 3]};
            *reinterpret_cast<float4*>(&dst[m * 64 + d0 + j4 * 4]) = o;
        }
        if ((t & 3) == 0) dst[4096 + m] += ks;
    }
}

// Reduce 8 chunk partials -> kv (64x64) + ksum (64) per head
__global__ __launch_bounds__(256)
void kv_reduce_kernel(const float* __restrict__ partial, float* __restrict__ kvout)
{
    const int h = blockIdx.x;
    const int t = threadIdx.x;
    for (int idx = t; idx < 4160; idx += 256) {
        float s = 0.f;
        for (int c = 0; c < 8; ++c)
            s += partial[((size_t)h * 8 + c) * 4160 + idx];
        kvout[(size_t)h * 4160 + idx] = s;
    }
}

// ---------------------------------------------------------------------------
// context per (h, 64-row L tile) for ONE batch:
// RoPE(q) -> q' = relu(q_rot @ proj[h]) -> ctx = (q' @ kv) / (q'.ksum + 1e-4)
// qb: [4096][1024] (q at col h*64); ctxb: [4096][1024] written at col h*64.
// ---------------------------------------------------------------------------
__global__ __launch_bounds__(256)
void context_kernel(const float* __restrict__ qb, const float* __restrict__ cosb,
                    const float* __restrict__ sinb, const float* __restrict__ proj,
                    const float* __restrict__ kvsum, float* __restrict__ ctxb)
{
    const int lt = blockIdx.x;   // 0..63
    const int h  = blockIdx.y;   // 0..15
    const int t = threadIdx.x;

    __shared__ float bufA[64][68];  // q_rot, then reused for kv
    __shared__ float qp[64][68];    // q'
    __shared__ float pj[64][64];
    __shared__ float ksum[64];

    for (int i = t; i < 1024; i += 256)
        *reinterpret_cast<float4*>(&pj[0][0] + (size_t)i * 4) =
            *reinterpret_cast<const float4*>(proj + (size_t)h * 4096 + (size_t)i * 4);
    if (t < 64) ksum[t] = kvsum[(size_t)h * 4160 + 4096 + t];

    const int rowL = lt * 64;
    #pragma unroll
    for (int i = 0; i < 8; ++i) {
        int p = t + i * 256;
        int l = p >> 5, i2 = p & 31;
        size_t base = (size_t)(rowL + l) * 1024 + h * HDIM + 2 * i2;
        float qr = qb[base], qi = qb[base + 1];
        float c = cosb[(size_t)(rowL + l) * 32 + i2];
        float s = sinb[(size_t)(rowL + l) * 32 + i2];
        bufA[l][2 * i2]     = qr * c - qi * s;
        bufA[l][2 * i2 + 1] = qr * s + qi * c;
    }
    __syncthreads();

    {
        int l = t >> 2, m0 = (t & 3) << 4;
        float a[16] = {};
        for (int d = 0; d < 64; ++d) {
            float ql = bufA[l][d];
            const float* pr = &pj[d][m0];
            #pragma unroll
            for (int j = 0; j < 16; ++j) a[j] = fmaf(ql, pr[j], a[j]);
        }
        #pragma unroll
        for (int j = 0; j < 16; ++j) qp[l][m0 + j] = fmaxf(a[j], 0.f);
    }
    __syncthreads();

    #pragma unroll
    for (int i = 0; i < 4; ++i) {
        int idx = t + i * 256;
        int mm = idx >> 4, dd = (idx & 15) << 2;
        *reinterpret_cast<float4*>(&bufA[mm][dd]) =
            *reinterpret_cast<const float4*>(&kvsum[(size_t)h * 4160 + mm * 64 + dd]);
    }
    __syncthreads();

    {
        int l = t >> 2, d0 = (t & 3) << 4;
        float a[16] = {};
        float nrm = 0.f;
        for (int mm = 0; mm < 64; ++mm) {
            float qv = qp[l][mm];
            nrm = fmaf(qv, ksum[mm], nrm);
            const float* kr = &bufA[mm][d0];
            #pragma unroll
            for (int j = 0; j < 16; ++j) a[j] = fmaf(qv, kr[j], a[j]);
        }
        float inv = 1.0f / (nrm + 1e-4f);
        size_t orow = (size_t)(rowL + l) * 1024 + h * HDIM + d0;
        #pragma unroll
        for (int j4 = 0; j4 < 4; ++j4) {
            float4 o = {a[j4 * 4 + 0] * inv, a[j4 * 4 + 1] * inv,
                        a[j4 * 4 + 2] * inv, a[j4 * 4 + 3] * inv};
            *reinterpret_cast<float4*>(&ctxb[orow + j4 * 4]) = o;
        }
    }
}

extern "C" void kernel_launch(void* const* d_in, const int* in_sizes, int n_in,
                              void* d_out, int out_size, void* d_ws, size_t ws_size,
                              hipStream_t stream)
{
    const float* x    = (const float*)d_in[0];
    const float* fcos = (const float*)d_in[1];
    const float* fsin = (const float*)d_in[2];
    const float* mask = (const float*)d_in[3];
    const float* Wqkv = (const float*)d_in[4];
    const float* bqkv = (const float*)d_in[5];
    const float* proj = (const float*)d_in[6];
    const float* Wout = (const float*)d_in[7];
    const float* bout = (const float*)d_in[8];
    float* out = (float*)d_out;

    // Workspace: 3 x 16.78 MB regions + partials = 52.7 MB total
    float* R0 = (float*)d_ws;          // KV-half fp32 [2048][2048] / q fp32 [4096][1024] / ctx hi+lo
    float* R1 = R0 + 4194304;          // x hi+lo bf16 / ctx fp32 [4096][1024]
    float* R2 = R1 + 4194304;          // weights hi/lo (persistent, transposed)
    float* R3 = R2 + 4194304;          // partials [16][8][4160]
    float* R4 = R3 + 532480;           // kvsum [16][4160]

    unsigned short* xh  = (unsigned short*)R1;
    unsigned short* xl  = xh + 4194304;
    unsigned short* Wqh = (unsigned short*)R2;      // Wqkv^T hi: [3072][1024]
    unsigned short* Wql = Wqh + 3145728;
    unsigned short* Woh = Wql + 3145728;            // Wout^T hi: [1024][1024]
    unsigned short* Wol = Woh + 1048576;
    unsigned short* ch  = (unsigned short*)R0;      // ctx hi/lo (after q is dead)
    unsigned short* cl  = ch + 4194304;

    // Weight conversions (once per launch), transposed for B-operand K-contiguity
    convert_T_hilo<<<dim3(3072 / 64, 1024 / 64), 256, 0, stream>>>(Wqkv, Wqh, Wql, 1024, 3072);
    convert_T_hilo<<<dim3(1024 / 64, 1024 / 64), 256, 0, stream>>>(Wout, Woh, Wol, 1024, 1024);

    for (int b = 0; b < 4; ++b) {
        const float* xb = x + (size_t)b * 4194304;

        convert_hilo<<<4096, 256, 0, stream>>>(xb, xh, xl, 4194304);

        // K,V in two L-halves; kv partials accumulate across halves
        for (int half = 0; half < 2; ++half) {
            gemm3_kernel<<<dim3(16, 16), 256, 0, stream>>>(
                xh + (size_t)half * 2048 * 1024, xl + (size_t)half * 2048 * 1024,
                Wqh + (size_t)1024 * 1024, Wql + (size_t)1024 * 1024,
                bqkv + 1024, R0, 1024, 2048);
            kv_partial_kernel<<<dim3(8, 16), 256, 0, stream>>>(
                R0, fcos + (size_t)half * 2048 * 32, fsin + (size_t)half * 2048 * 32,
                mask + (size_t)b * 4096 + half * 2048, proj, R3, half == 0 ? 1 : 0);
        }
        kv_reduce_kernel<<<16, 256, 0, stream>>>(R3, R4);

        // Q (full 4096 rows) -> R0
        gemm3_kernel<<<dim3(8, 32), 256, 0, stream>>>(
            xh, xl, Wqh, Wql, bqkv, R0, 1024, 1024);

        // context -> R1 (x is dead)
        context_kernel<<<dim3(64, 16), 256, 0, stream>>>(R0, fcos, fsin, proj, R4, R1);

        // ctx -> hi/lo into R0 (q is dead)
        convert_hilo<<<4096, 256, 0, stream>>>(R1, ch, cl, 4194304);

        // out_b = ctx @ Wout + bout
        gemm3_kernel<<<dim3(8, 32), 256, 0, stream>>>(
            ch, cl, Woh, Wol, bout, out + (size_t)b * 4194304, 1024, 1024);
    }
}

// Round 4
// 1012.605 us; speedup vs baseline: 2.2124x; 1.1698x over previous
//
#include <hip/hip_runtime.h>

#define LSEQ   4096
#define EMBED  1024
#define NHEADS 16
#define HDIM   64
#define QKV_N  3072

typedef __attribute__((ext_vector_type(8))) short bf16x8;
typedef __attribute__((ext_vector_type(4))) float f32x4;

// round-to-nearest-even fp32 -> bf16 (bit pattern), no header dependence
__device__ inline unsigned short bf16_rne(float x) {
    unsigned int u = __float_as_uint(x);
    unsigned int r = (u + 0x7fffu + ((u >> 16) & 1u)) >> 16;
    return (unsigned short)r;
}
__device__ inline float bf16_to_f32(unsigned short h) {
    return __uint_as_float(((unsigned int)h) << 16);
}

// ---------------------------------------------------------------------------
// Convert contiguous fp32 -> hi/lo bf16 arrays. n multiple of 1024.
// ---------------------------------------------------------------------------
__global__ __launch_bounds__(256)
void convert_hilo(const float* __restrict__ in, unsigned short* __restrict__ hi,
                  unsigned short* __restrict__ lo, int n)
{
    int i = (blockIdx.x * 256 + threadIdx.x) << 2;
    if (i >= n) return;
    float4 v = *reinterpret_cast<const float4*>(&in[i]);
    float a[4] = {v.x, v.y, v.z, v.w};
    unsigned short hh[4], ll[4];
    #pragma unroll
    for (int j = 0; j < 4; ++j) {
        hh[j] = bf16_rne(a[j]);
        ll[j] = bf16_rne(a[j] - bf16_to_f32(hh[j]));
    }
    *reinterpret_cast<ushort4*>(&hi[i]) = make_ushort4(hh[0], hh[1], hh[2], hh[3]);
    *reinterpret_cast<ushort4*>(&lo[i]) = make_ushort4(ll[0], ll[1], ll[2], ll[3]);
}

// ---------------------------------------------------------------------------
// Convert fp32 W[K][N] -> TRANSPOSED hi/lo bf16 Wt[N][K] (for B-operand).
// 64x64 LDS tile transpose. K,N multiples of 64.
// ---------------------------------------------------------------------------
__global__ __launch_bounds__(256)
void convert_T_hilo(const float* __restrict__ in, unsigned short* __restrict__ hi,
                    unsigned short* __restrict__ lo, int K, int N)
{
    __shared__ float tile[64][65];
    const int n0 = blockIdx.x * 64, k0 = blockIdx.y * 64;
    const int t = threadIdx.x;
    #pragma unroll
    for (int i = 0; i < 16; ++i) {
        int idx = t + i * 256;           // 0..4095
        int r = idx >> 6, c = idx & 63;  // k-local, n-local
        tile[r][c] = in[(size_t)(k0 + r) * N + n0 + c];
    }
    __syncthreads();
    #pragma unroll
    for (int i = 0; i < 16; ++i) {
        int idx = t + i * 256;
        int r = idx >> 6, c = idx & 63;  // n-local, k-local
        float v = tile[c][r];
        unsigned short h = bf16_rne(v);
        unsigned short l = bf16_rne(v - bf16_to_f32(h));
        size_t o = (size_t)(n0 + r) * K + k0 + c;
        hi[o] = h;
        lo[o] = l;
    }
}

// ---------------------------------------------------------------------------
// bf16x3 split GEMM v2: C = A @ B^T_stored + bias (logical C = A @ B + bias)
// A_hi/A_lo: [M][K] bf16 (lda=K). Bt_hi/Bt_lo: [N][K] bf16 (ldb=K). C fp32.
// 128x128 tile, BK=32, 4 waves, mfma_f32_16x16x32_bf16 x3 products.
// NEW: double-buffered LDS + 1-ahead prefetch (hides staging latency at
// 1 block/CU) and XOR-swizzled tile layout (16B chunk c -> c ^ ((row>>1)&3)),
// applied on the global_load_lds SOURCE address (LDS dest stays linear,
// m104/m173) and on fragment ds_reads: 8-way bank conflict -> 2-way (free).
// ---------------------------------------------------------------------------
__global__ __launch_bounds__(256)
void gemm3_kernel(const unsigned short* __restrict__ Ah, const unsigned short* __restrict__ Al,
                  const unsigned short* __restrict__ Bh, const unsigned short* __restrict__ Bl,
                  const float* __restrict__ bias, float* __restrict__ C,
                  int K, int ldc)
{
    // [buf][tile: Ah,Al,Bh,Bl][128 rows x 32 cols bf16] = 64 KB
    __shared__ __align__(16) unsigned short lds[2][4][4096];

    const int t = threadIdx.x;
    const int wave = t >> 6, lane = t & 63;
    const int wr = wave >> 1, wc = wave & 1;
    const int rowBase = blockIdx.y * 128;
    const int colBase = blockIdx.x * 128;
    const int fr = lane & 15, fq = lane >> 4;

    // staging map: wave w stages tile w, 8 issues x 64 lanes x 16B.
    // LDS chunk at lane*16 within each 1KB row-group holds global k-chunk
    // (lane&3) ^ ((row>>1)&3)  [row = i*16 + (lane>>2); (row>>1)&3 == (lane>>3)&3]
    const unsigned short* src = (wave == 0) ? Ah : (wave == 1) ? Al : (wave == 2) ? Bh : Bl;
    const int tileRow0 = (wave < 2) ? rowBase : colBase;
    const int sRow = lane >> 2;
    const int sChunkElems = (((lane & 3) ^ ((lane >> 3) & 3)) << 3);

    f32x4 acc[4][4] = {};

    const int NT = K >> 5;

    // prologue: stage tile 0 into buffer 0
    #pragma unroll
    for (int i = 0; i < 8; ++i) {
        const unsigned short* g = src + (size_t)(tileRow0 + i * 16 + sRow) * K + sChunkElems;
        __builtin_amdgcn_global_load_lds(
            (const __attribute__((address_space(1))) void*)g,
            (__attribute__((address_space(3))) void*)&lds[0][wave][i * 512], 16, 0, 0);
    }
    __syncthreads();

    for (int tI = 0; tI < NT; ++tI) {
        const int cur = tI & 1;

        // prefetch next K-tile into the other buffer (in flight across MFMA phase)
        if (tI + 1 < NT) {
            const int k0 = (tI + 1) << 5;
            #pragma unroll
            for (int i = 0; i < 8; ++i) {
                const unsigned short* g =
                    src + (size_t)(tileRow0 + i * 16 + sRow) * K + k0 + sChunkElems;
                __builtin_amdgcn_global_load_lds(
                    (const __attribute__((address_space(1))) void*)g,
                    (__attribute__((address_space(3))) void*)&lds[cur ^ 1][wave][i * 512], 16, 0, 0);
            }
        }

        // fragment reads (swizzled) + MFMA
        bf16x8 ah[4], al[4], bh[4], bl[4];
        #pragma unroll
        for (int m = 0; m < 4; ++m) {
            int r = wr * 64 + m * 16 + fr;
            int off = r * 32 + ((fq ^ ((r >> 1) & 3)) << 3);   // shorts
            ah[m] = *reinterpret_cast<const bf16x8*>(&lds[cur][0][off]);
            al[m] = *reinterpret_cast<const bf16x8*>(&lds[cur][1][off]);
        }
        #pragma unroll
        for (int n = 0; n < 4; ++n) {
            int r = wc * 64 + n * 16 + fr;
            int off = r * 32 + ((fq ^ ((r >> 1) & 3)) << 3);
            bh[n] = *reinterpret_cast<const bf16x8*>(&lds[cur][2][off]);
            bl[n] = *reinterpret_cast<const bf16x8*>(&lds[cur][3][off]);
        }
        #pragma unroll
        for (int m = 0; m < 4; ++m)
            #pragma unroll
            for (int n = 0; n < 4; ++n) {
                acc[m][n] = __builtin_amdgcn_mfma_f32_16x16x32_bf16(ah[m], bh[n], acc[m][n], 0, 0, 0);
                acc[m][n] = __builtin_amdgcn_mfma_f32_16x16x32_bf16(ah[m], bl[n], acc[m][n], 0, 0, 0);
                acc[m][n] = __builtin_amdgcn_mfma_f32_16x16x32_bf16(al[m], bh[n], acc[m][n], 0, 0, 0);
            }

        __syncthreads();  // drains this iter's prefetch (overlapped with MFMA above)
    }

    // epilogue: C/D frag mapping col=lane&15, row=(lane>>4)*4+reg (m89-verified)
    #pragma unroll
    for (int m = 0; m < 4; ++m) {
        #pragma unroll
        for (int n = 0; n < 4; ++n) {
            int col = colBase + wc * 64 + n * 16 + fr;
            float bv = bias[col];
            #pragma unroll
            for (int r = 0; r < 4; ++r) {
                int row = rowBase + wr * 64 + m * 16 + fq * 4 + r;
                C[(size_t)row * ldc + col] = acc[m][n][r] + bv;
            }
        }
    }
}

// ---------------------------------------------------------------------------
// kv partial per (h, chunk) for ONE L-half (2048 rows). chunk = 256 rows.
// kvb: [2048][2048] fp32 (k at col h*64, v at col 1024 + h*64).
// cos/sin/mask pointers pre-offset to the half. first=1 -> overwrite partials.
// partial layout: [h][8 chunks][4160] (4096 = kv [m][d], +64 = ksum)
// ---------------------------------------------------------------------------
__global__ __launch_bounds__(256)
void kv_partial_kernel(const float* __restrict__ kvb, const float* __restrict__ cosb,
                       const float* __restrict__ sinb, const float* __restrict__ maskb,
                       const float* __restrict__ proj, float* __restrict__ partial,
                       int first)
{
    const int chunk = blockIdx.x;   // 0..7
    const int h     = blockIdx.y;   // 0..15
    const int t = threadIdx.x;

    __shared__ float bufA[64][68];  // k_rot, then v (reused)
    __shared__ float kp[64][68];    // k'
    __shared__ float pj[64][64];    // proj[h], [d][m]

    for (int i = t; i < 1024; i += 256)
        *reinterpret_cast<float4*>(&pj[0][0] + (size_t)i * 4) =
            *reinterpret_cast<const float4*>(proj + (size_t)h * 4096 + (size_t)i * 4);

    const int m  = t >> 2;          // 0..63
    const int d0 = (t & 3) << 4;    // 0,16,32,48
    float acc[16] = {};
    float ks = 0.f;

    for (int sub = 0; sub < 4; ++sub) {
        const int rowL = chunk * 256 + sub * 64;
        __syncthreads();

        // RoPE-load K tile: 64 rows x 32 pairs
        #pragma unroll
        for (int i = 0; i < 8; ++i) {
            int p = t + i * 256;
            int l = p >> 5, i2 = p & 31;
            size_t base = (size_t)(rowL + l) * 2048 + h * HDIM + 2 * i2;
            float kr = kvb[base], ki = kvb[base + 1];
            float c = cosb[(size_t)(rowL + l) * 32 + i2];
            float s = sinb[(size_t)(rowL + l) * 32 + i2];
            bufA[l][2 * i2]     = kr * c - ki * s;
            bufA[l][2 * i2 + 1] = kr * s + ki * c;
        }
        __syncthreads();

        // k' = relu(k_rot @ proj) * mask
        {
            int l = t >> 2, m0 = (t & 3) << 4;
            float a[16] = {};
            for (int d = 0; d < 64; ++d) {
                float kl = bufA[l][d];
                const float* pr = &pj[d][m0];
                #pragma unroll
                for (int j = 0; j < 16; ++j) a[j] = fmaf(kl, pr[j], a[j]);
            }
            float mv = maskb[rowL + l];
            #pragma unroll
            for (int j = 0; j < 16; ++j) kp[l][m0 + j] = fmaxf(a[j], 0.f) * mv;
        }
        __syncthreads();

        // load masked V into bufA
        #pragma unroll
        for (int i = 0; i < 4; ++i) {
            int idx = t + i * 256;
            int l = idx >> 4, dd = (idx & 15) << 2;
            float4 v = *reinterpret_cast<const float4*>(
                &kvb[(size_t)(rowL + l) * 2048 + 1024 + h * HDIM + dd]);
            float mv = maskb[rowL + l];
            v.x *= mv; v.y *= mv; v.z *= mv; v.w *= mv;
            *reinterpret_cast<float4*>(&bufA[l][dd]) = v;
        }
        __syncthreads();

        for (int l = 0; l < 64; ++l) {
            float kl = kp[l][m];
            ks += kl;
            const float* vr = &bufA[l][d0];
            #pragma unroll
            for (int j = 0; j < 16; ++j) acc[j] = fmaf(kl, vr[j], acc[j]);
        }
    }

    float* dst = partial + ((size_t)h * 8 + chunk) * 4160;
    if (first) {
        #pragma unroll
        for (int j4 = 0; j4 < 4; ++j4) {
            float4 o = {acc[j4 * 4 + 0], acc[j4 * 4 + 1], acc[j4 * 4 + 2], acc[j4 * 4 + 3]};
            *reinterpret_cast<float4*>(&dst[m * 64 + d0 + j4 * 4]) = o;
        }
        if ((t & 3) == 0) dst[4096 + m] = ks;
    } else {
        #pragma unroll
        for (int j4 = 0; j4 < 4; ++j4) {
            float4 p = *reinterpret_cast<const float4*>(&dst[m * 64 + d0 + j4 * 4]);
            float4 o = {p.x + acc[j4 * 4 + 0], p.y + acc[j4 * 4 + 1],
                        p.z + acc[j4 * 4 + 2], p.w + acc[j4 * 4 + 3]};
            *reinterpret_cast<float4*>(&dst[m * 64 + d0 + j4 * 4]) = o;
        }
        if ((t & 3) == 0) dst[4096 + m] += ks;
    }
}

// Reduce 8 chunk partials -> kv (64x64) + ksum (64) per head
__global__ __launch_bounds__(256)
void kv_reduce_kernel(const float* __restrict__ partial, float* __restrict__ kvout)
{
    const int h = blockIdx.x;
    const int t = threadIdx.x;
    for (int idx = t; idx < 4160; idx += 256) {
        float s = 0.f;
        for (int c = 0; c < 8; ++c)
            s += partial[((size_t)h * 8 + c) * 4160 + idx];
        kvout[(size_t)h * 4160 + idx] = s;
    }
}

// ---------------------------------------------------------------------------
// context per (h, 64-row L tile) for ONE batch:
// RoPE(q) -> q' = relu(q_rot @ proj[h]) -> ctx = (q' @ kv) / (q'.ksum + 1e-4)
// qb: [4096][1024] (q at col h*64); ctxb: [4096][1024] written at col h*64.
// ---------------------------------------------------------------------------
__global__ __launch_bounds__(256)
void context_kernel(const float* __restrict__ qb, const float* __restrict__ cosb,
                    const float* __restrict__ sinb, const float* __restrict__ proj,
                    const float* __restrict__ kvsum, float* __restrict__ ctxb)
{
    const int lt = blockIdx.x;   // 0..63
    const int h  = blockIdx.y;   // 0..15
    const int t = threadIdx.x;

    __shared__ float bufA[64][68];  // q_rot, then reused for kv
    __shared__ float qp[64][68];    // q'
    __shared__ float pj[64][64];
    __shared__ float ksum[64];

    for (int i = t; i < 1024; i += 256)
        *reinterpret_cast<float4*>(&pj[0][0] + (size_t)i * 4) =
            *reinterpret_cast<const float4*>(proj + (size_t)h * 4096 + (size_t)i * 4);
    if (t < 64) ksum[t] = kvsum[(size_t)h * 4160 + 4096 + t];

    const int rowL = lt * 64;
    #pragma unroll
    for (int i = 0; i < 8; ++i) {
        int p = t + i * 256;
        int l = p >> 5, i2 = p & 31;
        size_t base = (size_t)(rowL + l) * 1024 + h * HDIM + 2 * i2;
        float qr = qb[base], qi = qb[base + 1];
        float c = cosb[(size_t)(rowL + l) * 32 + i2];
        float s = sinb[(size_t)(rowL + l) * 32 + i2];
        bufA[l][2 * i2]     = qr * c - qi * s;
        bufA[l][2 * i2 + 1] = qr * s + qi * c;
    }
    __syncthreads();

    {
        int l = t >> 2, m0 = (t & 3) << 4;
        float a[16] = {};
        for (int d = 0; d < 64; ++d) {
            float ql = bufA[l][d];
            const float* pr = &pj[d][m0];
            #pragma unroll
            for (int j = 0; j < 16; ++j) a[j] = fmaf(ql, pr[j], a[j]);
        }
        #pragma unroll
        for (int j = 0; j < 16; ++j) qp[l][m0 + j] = fmaxf(a[j], 0.f);
    }
    __syncthreads();

    #pragma unroll
    for (int i = 0; i < 4; ++i) {
        int idx = t + i * 256;
        int mm = idx >> 4, dd = (idx & 15) << 2;
        *reinterpret_cast<float4*>(&bufA[mm][dd]) =
            *reinterpret_cast<const float4*>(&kvsum[(size_t)h * 4160 + mm * 64 + dd]);
    }
    __syncthreads();

    {
        int l = t >> 2, d0 = (t & 3) << 4;
        float a[16] = {};
        float nrm = 0.f;
        for (int mm = 0; mm < 64; ++mm) {
            float qv = qp[l][mm];
            nrm = fmaf(qv, ksum[mm], nrm);
            const float* kr = &bufA[mm][d0];
            #pragma unroll
            for (int j = 0; j < 16; ++j) a[j] = fmaf(qv, kr[j], a[j]);
        }
        float inv = 1.0f / (nrm + 1e-4f);
        size_t orow = (size_t)(rowL + l) * 1024 + h * HDIM + d0;
        #pragma unroll
        for (int j4 = 0; j4 < 4; ++j4) {
            float4 o = {a[j4 * 4 + 0] * inv, a[j4 * 4 + 1] * inv,
                        a[j4 * 4 + 2] * inv, a[j4 * 4 + 3] * inv};
            *reinterpret_cast<float4*>(&ctxb[orow + j4 * 4]) = o;
        }
    }
}

extern "C" void kernel_launch(void* const* d_in, const int* in_sizes, int n_in,
                              void* d_out, int out_size, void* d_ws, size_t ws_size,
                              hipStream_t stream)
{
    const float* x    = (const float*)d_in[0];
    const float* fcos = (const float*)d_in[1];
    const float* fsin = (const float*)d_in[2];
    const float* mask = (const float*)d_in[3];
    const float* Wqkv = (const float*)d_in[4];
    const float* bqkv = (const float*)d_in[5];
    const float* proj = (const float*)d_in[6];
    const float* Wout = (const float*)d_in[7];
    const float* bout = (const float*)d_in[8];
    float* out = (float*)d_out;

    // Workspace: 3 x 16.78 MB regions + partials = 52.7 MB total (proven size)
    float* R0 = (float*)d_ws;          // KV-half fp32 [2048][2048] / q fp32 [4096][1024] / ctx hi+lo
    float* R1 = R0 + 4194304;          // x hi+lo bf16 / ctx fp32 [4096][1024]
    float* R2 = R1 + 4194304;          // weights hi/lo (persistent, transposed)
    float* R3 = R2 + 4194304;          // partials [16][8][4160]
    float* R4 = R3 + 532480;           // kvsum [16][4160]

    unsigned short* xh  = (unsigned short*)R1;
    unsigned short* xl  = xh + 4194304;
    unsigned short* Wqh = (unsigned short*)R2;      // Wqkv^T hi: [3072][1024]
    unsigned short* Wql = Wqh + 3145728;
    unsigned short* Woh = Wql + 3145728;            // Wout^T hi: [1024][1024]
    unsigned short* Wol = Woh + 1048576;
    unsigned short* ch  = (unsigned short*)R0;      // ctx hi/lo (after q is dead)
    unsigned short* cl  = ch + 4194304;

    // Weight conversions (once per launch), transposed for B-operand K-contiguity
    convert_T_hilo<<<dim3(3072 / 64, 1024 / 64), 256, 0, stream>>>(Wqkv, Wqh, Wql, 1024, 3072);
    convert_T_hilo<<<dim3(1024 / 64, 1024 / 64), 256, 0, stream>>>(Wout, Woh, Wol, 1024, 1024);

    for (int b = 0; b < 4; ++b) {
        const float* xb = x + (size_t)b * 4194304;

        convert_hilo<<<4096, 256, 0, stream>>>(xb, xh, xl, 4194304);

        // K,V in two L-halves; kv partials accumulate across halves
        for (int half = 0; half < 2; ++half) {
            gemm3_kernel<<<dim3(16, 16), 256, 0, stream>>>(
                xh + (size_t)half * 2048 * 1024, xl + (size_t)half * 2048 * 1024,
                Wqh + (size_t)1024 * 1024, Wql + (size_t)1024 * 1024,
                bqkv + 1024, R0, 1024, 2048);
            kv_partial_kernel<<<dim3(8, 16), 256, 0, stream>>>(
                R0, fcos + (size_t)half * 2048 * 32, fsin + (size_t)half * 2048 * 32,
                mask + (size_t)b * 4096 + half * 2048, proj, R3, half == 0 ? 1 : 0);
        }
        kv_reduce_kernel<<<16, 256, 0, stream>>>(R3, R4);

        // Q (full 4096 rows) -> R0
        gemm3_kernel<<<dim3(8, 32), 256, 0, stream>>>(
            xh, xl, Wqh, Wql, bqkv, R0, 1024, 1024);

        // context -> R1 (x is dead)
        context_kernel<<<dim3(64, 16), 256, 0, stream>>>(R0, fcos, fsin, proj, R4, R1);

        // ctx -> hi/lo into R0 (q is dead)
        convert_hilo<<<4096, 256, 0, stream>>>(R1, ch, cl, 4194304);

        // out_b = ctx @ Wout + bout
        gemm3_kernel<<<dim3(8, 32), 256, 0, stream>>>(
            ch, cl, Woh, Wol, bout, out + (size_t)b * 4194304, 1024, 1024);
    }
}

// Round 5
// 982.765 us; speedup vs baseline: 2.2796x; 1.0304x over previous
//
#include <hip/hip_runtime.h>

#define LSEQ   4096
#define EMBED  1024
#define NHEADS 16
#define HDIM   64
#define QKV_N  3072

typedef __attribute__((ext_vector_type(8))) short bf16x8;
typedef __attribute__((ext_vector_type(4))) float f32x4;

// round-to-nearest-even fp32 -> bf16 (bit pattern), no header dependence
__device__ inline unsigned short bf16_rne(float x) {
    unsigned int u = __float_as_uint(x);
    unsigned int r = (u + 0x7fffu + ((u >> 16) & 1u)) >> 16;
    return (unsigned short)r;
}
__device__ inline float bf16_to_f32(unsigned short h) {
    return __uint_as_float(((unsigned int)h) << 16);
}

// ---------------------------------------------------------------------------
// Convert contiguous fp32 -> hi/lo bf16 arrays. n multiple of 1024.
// ---------------------------------------------------------------------------
__global__ __launch_bounds__(256)
void convert_hilo(const float* __restrict__ in, unsigned short* __restrict__ hi,
                  unsigned short* __restrict__ lo, int n)
{
    int i = (blockIdx.x * 256 + threadIdx.x) << 2;
    if (i >= n) return;
    float4 v = *reinterpret_cast<const float4*>(&in[i]);
    float a[4] = {v.x, v.y, v.z, v.w};
    unsigned short hh[4], ll[4];
    #pragma unroll
    for (int j = 0; j < 4; ++j) {
        hh[j] = bf16_rne(a[j]);
        ll[j] = bf16_rne(a[j] - bf16_to_f32(hh[j]));
    }
    *reinterpret_cast<ushort4*>(&hi[i]) = make_ushort4(hh[0], hh[1], hh[2], hh[3]);
    *reinterpret_cast<ushort4*>(&lo[i]) = make_ushort4(ll[0], ll[1], ll[2], ll[3]);
}

// ---------------------------------------------------------------------------
// Convert fp32 W[K][N] -> TRANSPOSED hi/lo bf16 Wt[N][K] (for B-operand).
// 64x64 LDS tile transpose. K,N multiples of 64.
// ---------------------------------------------------------------------------
__global__ __launch_bounds__(256)
void convert_T_hilo(const float* __restrict__ in, unsigned short* __restrict__ hi,
                    unsigned short* __restrict__ lo, int K, int N)
{
    __shared__ float tile[64][65];
    const int n0 = blockIdx.x * 64, k0 = blockIdx.y * 64;
    const int t = threadIdx.x;
    #pragma unroll
    for (int i = 0; i < 16; ++i) {
        int idx = t + i * 256;           // 0..4095
        int r = idx >> 6, c = idx & 63;  // k-local, n-local
        tile[r][c] = in[(size_t)(k0 + r) * N + n0 + c];
    }
    __syncthreads();
    #pragma unroll
    for (int i = 0; i < 16; ++i) {
        int idx = t + i * 256;
        int r = idx >> 6, c = idx & 63;  // n-local, k-local
        float v = tile[c][r];
        unsigned short h = bf16_rne(v);
        unsigned short l = bf16_rne(v - bf16_to_f32(h));
        size_t o = (size_t)(n0 + r) * K + k0 + c;
        hi[o] = h;
        lo[o] = l;
    }
}

// ---------------------------------------------------------------------------
// bf16x3 split GEMM v3: C = A @ B^T_stored + bias (logical C = A @ B + bias)
// A_hi/A_lo: [M][K] bf16 (lda=K). Bt_hi/Bt_lo: [N][K] bf16 (ldb=K). C fp32.
// 128x64 tile (grid 2x vs v2 -> 2 blocks/CU, 2 waves/SIMD), BK=32, 4 waves,
// each wave owns a 64x32 output sub-tile (4x2 fragments, 24 MFMA / K-step).
// Double-buffered 1-ahead prefetch via global_load_lds(16B), XOR-swizzled
// tiles (16B chunk c -> c ^ ((row>>1)&3)) on source addr + frag reads.
// LDS 48 KB. M mult of 128, N mult of 64, K mult of 32.
// ---------------------------------------------------------------------------
__global__ __launch_bounds__(256)
void gemm3_kernel(const unsigned short* __restrict__ Ah, const unsigned short* __restrict__ Al,
                  const unsigned short* __restrict__ Bh, const unsigned short* __restrict__ Bl,
                  const float* __restrict__ bias, float* __restrict__ C,
                  int K, int ldc)
{
    // shorts: Ah[128][32] @0, Al @4096, Bh[64][32] @8192, Bl @10240 ; x2 buffers
    __shared__ __align__(16) unsigned short lds[2][12288];   // 48 KB

    const int t = threadIdx.x;
    const int wave = t >> 6, lane = t & 63;
    const int wr = wave >> 1, wc = wave & 1;     // wave tile: 64 rows x 32 cols
    const int rowBase = blockIdx.y * 128;
    const int colBase = blockIdx.x * 64;
    const int fr = lane & 15, fq = lane >> 4;

    // staging: wave 0->Ah(8 iss), 1->Al(8), 2->Bh(4), 3->Bl(4); 16B/lane
    const unsigned short* src = (wave == 0) ? Ah : (wave == 1) ? Al : (wave == 2) ? Bh : Bl;
    const int tileRow0 = (wave < 2) ? rowBase : colBase;
    const int ldsOff = (wave < 2) ? wave * 4096 : 8192 + (wave - 2) * 2048;
    const int sRow = lane >> 2;
    const int sChunk = (((lane & 3) ^ ((lane >> 3) & 3)) << 3);   // swizzled k-chunk (elems)

    f32x4 acc[4][2] = {};
    const int NT = K >> 5;

    // prologue: stage tile 0 into buffer 0
    if (wave < 2) {
        #pragma unroll
        for (int i = 0; i < 8; ++i) {
            const unsigned short* g = src + (size_t)(tileRow0 + i * 16 + sRow) * K + sChunk;
            __builtin_amdgcn_global_load_lds(
                (const __attribute__((address_space(1))) void*)g,
                (__attribute__((address_space(3))) void*)&lds[0][ldsOff + i * 512], 16, 0, 0);
        }
    } else {
        #pragma unroll
        for (int i = 0; i < 4; ++i) {
            const unsigned short* g = src + (size_t)(tileRow0 + i * 16 + sRow) * K + sChunk;
            __builtin_amdgcn_global_load_lds(
                (const __attribute__((address_space(1))) void*)g,
                (__attribute__((address_space(3))) void*)&lds[0][ldsOff + i * 512], 16, 0, 0);
        }
    }
    __syncthreads();

    for (int tI = 0; tI < NT; ++tI) {
        const int cur = tI & 1;

        // prefetch next K-tile into the other buffer (in flight across MFMA phase)
        if (tI + 1 < NT) {
            const int k0 = (tI + 1) << 5;
            if (wave < 2) {
                #pragma unroll
                for (int i = 0; i < 8; ++i) {
                    const unsigned short* g =
                        src + (size_t)(tileRow0 + i * 16 + sRow) * K + k0 + sChunk;
                    __builtin_amdgcn_global_load_lds(
                        (const __attribute__((address_space(1))) void*)g,
                        (__attribute__((address_space(3))) void*)&lds[cur ^ 1][ldsOff + i * 512], 16, 0, 0);
                }
            } else {
                #pragma unroll
                for (int i = 0; i < 4; ++i) {
                    const unsigned short* g =
                        src + (size_t)(tileRow0 + i * 16 + sRow) * K + k0 + sChunk;
                    __builtin_amdgcn_global_load_lds(
                        (const __attribute__((address_space(1))) void*)g,
                        (__attribute__((address_space(3))) void*)&lds[cur ^ 1][ldsOff + i * 512], 16, 0, 0);
                }
            }
        }

        // fragment reads (swizzled) + MFMA
        bf16x8 ah[4], al[4], bh[2], bl[2];
        #pragma unroll
        for (int m = 0; m < 4; ++m) {
            int r = wr * 64 + m * 16 + fr;
            int off = r * 32 + ((fq ^ ((r >> 1) & 3)) << 3);
            ah[m] = *reinterpret_cast<const bf16x8*>(&lds[cur][off]);
            al[m] = *reinterpret_cast<const bf16x8*>(&lds[cur][4096 + off]);
        }
        #pragma unroll
        for (int n = 0; n < 2; ++n) {
            int r = wc * 32 + n * 16 + fr;
            int off = r * 32 + ((fq ^ ((r >> 1) & 3)) << 3);
            bh[n] = *reinterpret_cast<const bf16x8*>(&lds[cur][8192 + off]);
            bl[n] = *reinterpret_cast<const bf16x8*>(&lds[cur][10240 + off]);
        }
        #pragma unroll
        for (int m = 0; m < 4; ++m)
            #pragma unroll
            for (int n = 0; n < 2; ++n) {
                acc[m][n] = __builtin_amdgcn_mfma_f32_16x16x32_bf16(ah[m], bh[n], acc[m][n], 0, 0, 0);
                acc[m][n] = __builtin_amdgcn_mfma_f32_16x16x32_bf16(ah[m], bl[n], acc[m][n], 0, 0, 0);
                acc[m][n] = __builtin_amdgcn_mfma_f32_16x16x32_bf16(al[m], bh[n], acc[m][n], 0, 0, 0);
            }

        __syncthreads();  // drains this iter's prefetch (overlapped with MFMA above)
    }

    // epilogue: C/D frag mapping col=lane&15, row=(lane>>4)*4+reg (m89-verified)
    #pragma unroll
    for (int m = 0; m < 4; ++m) {
        #pragma unroll
        for (int n = 0; n < 2; ++n) {
            int col = colBase + wc * 32 + n * 16 + fr;
            float bv = bias[col];
            #pragma unroll
            for (int r = 0; r < 4; ++r) {
                int row = rowBase + wr * 64 + m * 16 + fq * 4 + r;
                C[(size_t)row * ldc + col] = acc[m][n][r] + bv;
            }
        }
    }
}

// ---------------------------------------------------------------------------
// kv partial per (h, chunk) for ONE L-half (2048 rows). chunk = 256 rows.
// kvb: [2048][2048] fp32 (k at col h*64, v at col 1024 + h*64).
// cos/sin/mask pointers pre-offset to the half. first=1 -> overwrite partials.
// partial layout: [h][8 chunks][4160] (4096 = kv [m][d], +64 = ksum)
// ---------------------------------------------------------------------------
__global__ __launch_bounds__(256)
void kv_partial_kernel(const float* __restrict__ kvb, const float* __restrict__ cosb,
                       const float* __restrict__ sinb, const float* __restrict__ maskb,
                       const float* __restrict__ proj, float* __restrict__ partial,
                       int first)
{
    const int chunk = blockIdx.x;   // 0..7
    const int h     = blockIdx.y;   // 0..15
    const int t = threadIdx.x;

    __shared__ float bufA[64][68];  // k_rot, then v (reused)
    __shared__ float kp[64][68];    // k'
    __shared__ float pj[64][64];    // proj[h], [d][m]

    for (int i = t; i < 1024; i += 256)
        *reinterpret_cast<float4*>(&pj[0][0] + (size_t)i * 4) =
            *reinterpret_cast<const float4*>(proj + (size_t)h * 4096 + (size_t)i * 4);

    const int m  = t >> 2;          // 0..63
    const int d0 = (t & 3) << 4;    // 0,16,32,48
    float acc[16] = {};
    float ks = 0.f;

    for (int sub = 0; sub < 4; ++sub) {
        const int rowL = chunk * 256 + sub * 64;
        __syncthreads();

        // RoPE-load K tile: 64 rows x 32 pairs
        #pragma unroll
        for (int i = 0; i < 8; ++i) {
            int p = t + i * 256;
            int l = p >> 5, i2 = p & 31;
            size_t base = (size_t)(rowL + l) * 2048 + h * HDIM + 2 * i2;
            float kr = kvb[base], ki = kvb[base + 1];
            float c = cosb[(size_t)(rowL + l) * 32 + i2];
            float s = sinb[(size_t)(rowL + l) * 32 + i2];
            bufA[l][2 * i2]     = kr * c - ki * s;
            bufA[l][2 * i2 + 1] = kr * s + ki * c;
        }
        __syncthreads();

        // k' = relu(k_rot @ proj) * mask
        {
            int l = t >> 2, m0 = (t & 3) << 4;
            float a[16] = {};
            for (int d = 0; d < 64; ++d) {
                float kl = bufA[l][d];
                const float* pr = &pj[d][m0];
                #pragma unroll
                for (int j = 0; j < 16; ++j) a[j] = fmaf(kl, pr[j], a[j]);
            }
            float mv = maskb[rowL + l];
            #pragma unroll
            for (int j = 0; j < 16; ++j) kp[l][m0 + j] = fmaxf(a[j], 0.f) * mv;
        }
        __syncthreads();

        // load masked V into bufA
        #pragma unroll
        for (int i = 0; i < 4; ++i) {
            int idx = t + i * 256;
            int l = idx >> 4, dd = (idx & 15) << 2;
            float4 v = *reinterpret_cast<const float4*>(
                &kvb[(size_t)(rowL + l) * 2048 + 1024 + h * HDIM + dd]);
            float mv = maskb[rowL + l];
            v.x *= mv; v.y *= mv; v.z *= mv; v.w *= mv;
            *reinterpret_cast<float4*>(&bufA[l][dd]) = v;
        }
        __syncthreads();

        for (int l = 0; l < 64; ++l) {
            float kl = kp[l][m];
            ks += kl;
            const float* vr = &bufA[l][d0];
            #pragma unroll
            for (int j = 0; j < 16; ++j) acc[j] = fmaf(kl, vr[j], acc[j]);
        }
    }

    float* dst = partial + ((size_t)h * 8 + chunk) * 4160;
    if (first) {
        #pragma unroll
        for (int j4 = 0; j4 < 4; ++j4) {
            float4 o = {acc[j4 * 4 + 0], acc[j4 * 4 + 1], acc[j4 * 4 + 2], acc[j4 * 4 + 3]};
            *reinterpret_cast<float4*>(&dst[m * 64 + d0 + j4 * 4]) = o;
        }
        if ((t & 3) == 0) dst[4096 + m] = ks;
    } else {
        #pragma unroll
        for (int j4 = 0; j4 < 4; ++j4) {
            float4 p = *reinterpret_cast<const float4*>(&dst[m * 64 + d0 + j4 * 4]);
            float4 o = {p.x + acc[j4 * 4 + 0], p.y + acc[j4 * 4 + 1],
                        p.z + acc[j4 * 4 + 2], p.w + acc[j4 * 4 + 3]};
            *reinterpret_cast<float4*>(&dst[m * 64 + d0 + j4 * 4]) = o;
        }
        if ((t & 3) == 0) dst[4096 + m] += ks;
    }
}

// Reduce 8 chunk partials -> kv (64x64) + ksum (64) per head
__global__ __launch_bounds__(256)
void kv_reduce_kernel(const float* __restrict__ partial, float* __restrict__ kvout)
{
    const int h = blockIdx.x;
    const int t = threadIdx.x;
    for (int idx = t; idx < 4160; idx += 256) {
        float s = 0.f;
        for (int c = 0; c < 8; ++c)
            s += partial[((size_t)h * 8 + c) * 4160 + idx];
        kvout[(size_t)h * 4160 + idx] = s;
    }
}

// ---------------------------------------------------------------------------
// context per (h, 64-row L tile) for ONE batch:
// RoPE(q) -> q' = relu(q_rot @ proj[h]) -> ctx = (q' @ kv) / (q'.ksum + 1e-4)
// qb: [4096][1024] (q at col h*64). NEW: writes ctx directly as hi/lo bf16
// (fused split for the out-GEMM A operand) -> drops a convert pass.
// ---------------------------------------------------------------------------
__global__ __launch_bounds__(256)
void context_kernel(const float* __restrict__ qb, const float* __restrict__ cosb,
                    const float* __restrict__ sinb, const float* __restrict__ proj,
                    const float* __restrict__ kvsum, unsigned short* __restrict__ ch,
                    unsigned short* __restrict__ cl)
{
    const int lt = blockIdx.x;   // 0..63
    const int h  = blockIdx.y;   // 0..15
    const int t = threadIdx.x;

    __shared__ float bufA[64][68];  // q_rot, then reused for kv
    __shared__ float qp[64][68];    // q'
    __shared__ float pj[64][64];
    __shared__ float ksum[64];

    for (int i = t; i < 1024; i += 256)
        *reinterpret_cast<float4*>(&pj[0][0] + (size_t)i * 4) =
            *reinterpret_cast<const float4*>(proj + (size_t)h * 4096 + (size_t)i * 4);
    if (t < 64) ksum[t] = kvsum[(size_t)h * 4160 + 4096 + t];

    const int rowL = lt * 64;
    #pragma unroll
    for (int i = 0; i < 8; ++i) {
        int p = t + i * 256;
        int l = p >> 5, i2 = p & 31;
        size_t base = (size_t)(rowL + l) * 1024 + h * HDIM + 2 * i2;
        float qr = qb[base], qi = qb[base + 1];
        float c = cosb[(size_t)(rowL + l) * 32 + i2];
        float s = sinb[(size_t)(rowL + l) * 32 + i2];
        bufA[l][2 * i2]     = qr * c - qi * s;
        bufA[l][2 * i2 + 1] = qr * s + qi * c;
    }
    __syncthreads();

    {
        int l = t >> 2, m0 = (t & 3) << 4;
        float a[16] = {};
        for (int d = 0; d < 64; ++d) {
            float ql = bufA[l][d];
            const float* pr = &pj[d][m0];
            #pragma unroll
            for (int j = 0; j < 16; ++j) a[j] = fmaf(ql, pr[j], a[j]);
        }
        #pragma unroll
        for (int j = 0; j < 16; ++j) qp[l][m0 + j] = fmaxf(a[j], 0.f);
    }
    __syncthreads();

    #pragma unroll
    for (int i = 0; i < 4; ++i) {
        int idx = t + i * 256;
        int mm = idx >> 4, dd = (idx & 15) << 2;
        *reinterpret_cast<float4*>(&bufA[mm][dd]) =
            *reinterpret_cast<const float4*>(&kvsum[(size_t)h * 4160 + mm * 64 + dd]);
    }
    __syncthreads();

    {
        int l = t >> 2, d0 = (t & 3) << 4;
        float a[16] = {};
        float nrm = 0.f;
        for (int mm = 0; mm < 64; ++mm) {
            float qv = qp[l][mm];
            nrm = fmaf(qv, ksum[mm], nrm);
            const float* kr = &bufA[mm][d0];
            #pragma unroll
            for (int j = 0; j < 16; ++j) a[j] = fmaf(qv, kr[j], a[j]);
        }
        float inv = 1.0f / (nrm + 1e-4f);
        size_t orow = (size_t)(rowL + l) * 1024 + h * HDIM + d0;
        #pragma unroll
        for (int j4 = 0; j4 < 4; ++j4) {
            unsigned short hh[4], ll[4];
            #pragma unroll
            for (int j = 0; j < 4; ++j) {
                float v = a[j4 * 4 + j] * inv;
                hh[j] = bf16_rne(v);
                ll[j] = bf16_rne(v - bf16_to_f32(hh[j]));
            }
            *reinterpret_cast<ushort4*>(&ch[orow + j4 * 4]) = make_ushort4(hh[0], hh[1], hh[2], hh[3]);
            *reinterpret_cast<ushort4*>(&cl[orow + j4 * 4]) = make_ushort4(ll[0], ll[1], ll[2], ll[3]);
        }
    }
}

extern "C" void kernel_launch(void* const* d_in, const int* in_sizes, int n_in,
                              void* d_out, int out_size, void* d_ws, size_t ws_size,
                              hipStream_t stream)
{
    const float* x    = (const float*)d_in[0];
    const float* fcos = (const float*)d_in[1];
    const float* fsin = (const float*)d_in[2];
    const float* mask = (const float*)d_in[3];
    const float* Wqkv = (const float*)d_in[4];
    const float* bqkv = (const float*)d_in[5];
    const float* proj = (const float*)d_in[6];
    const float* Wout = (const float*)d_in[7];
    const float* bout = (const float*)d_in[8];
    float* out = (float*)d_out;

    // Workspace (floats), ~52.9 MB total (proven size):
    float* R0 = (float*)d_ws;          // KV-half fp32 [2048][2048] / q fp32 [4096][1024]
    float* R1 = R0 + 4194304;          // x hi+lo bf16 / ctx hi+lo bf16
    float* R2 = R1 + 4194304;          // weights hi/lo (persistent, transposed)
    float* R3 = R2 + 4194304;          // partials [16][8][4160]
    float* R4 = R3 + 532480;           // kvsum [16][4160]

    unsigned short* xh  = (unsigned short*)R1;      // also ctx hi (x dead by then)
    unsigned short* xl  = xh + 4194304;             // also ctx lo
    unsigned short* Wqh = (unsigned short*)R2;      // Wqkv^T hi: [3072][1024]
    unsigned short* Wql = Wqh + 3145728;
    unsigned short* Woh = Wql + 3145728;            // Wout^T hi: [1024][1024]
    unsigned short* Wol = Woh + 1048576;

    // Weight conversions (once per launch), transposed for B-operand K-contiguity
    convert_T_hilo<<<dim3(3072 / 64, 1024 / 64), 256, 0, stream>>>(Wqkv, Wqh, Wql, 1024, 3072);
    convert_T_hilo<<<dim3(1024 / 64, 1024 / 64), 256, 0, stream>>>(Wout, Woh, Wol, 1024, 1024);

    for (int b = 0; b < 4; ++b) {
        const float* xb = x + (size_t)b * 4194304;

        convert_hilo<<<4096, 256, 0, stream>>>(xb, xh, xl, 4194304);

        // K,V in two L-halves; kv partials accumulate across halves
        for (int half = 0; half < 2; ++half) {
            gemm3_kernel<<<dim3(2048 / 64, 2048 / 128), 256, 0, stream>>>(
                xh + (size_t)half * 2048 * 1024, xl + (size_t)half * 2048 * 1024,
                Wqh + (size_t)1024 * 1024, Wql + (size_t)1024 * 1024,
                bqkv + 1024, R0, 1024, 2048);
            kv_partial_kernel<<<dim3(8, 16), 256, 0, stream>>>(
                R0, fcos + (size_t)half * 2048 * 32, fsin + (size_t)half * 2048 * 32,
                mask + (size_t)b * 4096 + half * 2048, proj, R3, half == 0 ? 1 : 0);
        }
        kv_reduce_kernel<<<16, 256, 0, stream>>>(R3, R4);

        // Q (full 4096 rows) -> R0
        gemm3_kernel<<<dim3(1024 / 64, 4096 / 128), 256, 0, stream>>>(
            xh, xl, Wqh, Wql, bqkv, R0, 1024, 1024);

        // context + normalization (fused RoPE + proj + relu + hi/lo split on Q)
        // writes ctx hi/lo over xh/xl (x dead for this batch)
        context_kernel<<<dim3(64, 16), 256, 0, stream>>>(
            R0, fcos, fsin, proj, R4, xh, xl);

        // out_b = ctx @ Wout + bout
        gemm3_kernel<<<dim3(1024 / 64, 4096 / 128), 256, 0, stream>>>(
            xh, xl, Woh, Wol, bout, out + (size_t)b * 4194304, 1024, 1024);
    }
}